// Round 2
// baseline (272.922 us; speedup 1.0000x reference)
//
#include <hip/hip_runtime.h>
#include <math.h>

#define N_SYM  128
#define BATCH  131072
#define B4     (BATCH / 4)     // row stride in float4 units = 32768
#define LEV    30.0f
#define SLOT   4               // symbols per LDS ring slot
#define NSLOT  4               // ring slots (64 KB total LDS)
#define PHASES (N_SYM / SLOT)  // 32

typedef float v4 __attribute__((ext_vector_type(4)));

// R4: producer/consumer wave specialization.
// R0-R3 established: per-wave VGPR-ring prefetch (any depth, any width) is
// stuck at ~76us, ~33% HBM, VALUBusy 24% -- the wave sits in s_waitcnt.
// The compiler's in-order vmcnt entangles the 4 loads + 1 store per
// iteration and a 148-VGPR ring forces conservative waits (classic HIP
// source-level-pipelining defeat, guide §5 m99-m141). Fix = T3/T4 pattern:
//   wave 1 (producer): global_load_lds f/e/p/m into a 4-slot LDS ring,
//     steady-state s_waitcnt vmcnt(32) -- 2 slots always in flight,
//     never drained to 0 in the main loop.
//   wave 0 (consumer): serial um-recurrence from LDS (ds_read_b128),
//     its vmcnt holds only output stores (never waited).
// Raw s_barrier (no __syncthreads -> no compiler vmcnt(0) drain).
// 512 blocks x 128 thr = 4 waves/CU. NT load hint dropped: L3 serves ~half
// the reads across dispatches (FETCH 131MB vs 256MB ideal) -- keep it.
__device__ __forceinline__ void gload16(const void* g, void* l)
{
    __builtin_amdgcn_global_load_lds(
        (const __attribute__((address_space(1))) void*)g,
        (__attribute__((address_space(3))) void*)l,
        16, 0, 0);
}

__device__ __forceinline__ float step1(float f, float e, float p, float m,
                                       float st, float mn, float mx,
                                       float* um)
{
    const float mrl = m * LEV;
    const float us  = *um * mrl;                // unused_size
    const float mps = fabsf(p) + us;            // max_pos_size
    const float adj = fminf((p * f > 0.0f) ? us : mps, 0.0f);
    const float nps = f * (mps - adj);

    float       a  = fabsf(nps);
    const float sg = copysignf(1.0f, nps);
    a = floorf(a / st) * st;
    a = (a < mn) ? 0.0f : a;
    a = fminf(a, mx);

    *um = (mps - a) / mrl;
    return e * (sg * a) + (1.0f - e) * p;
}

__global__ __launch_bounds__(128) void lle_pc_kernel(
    const float* __restrict__ frac,
    const float* __restrict__ exs,
    const float* __restrict__ pos,
    const float* __restrict__ mrate,
    const float* __restrict__ um0,
    const float* __restrict__ msm_min,
    const float* __restrict__ msm_step,
    const float* __restrict__ msm_max,
    float* __restrict__ out)
{
    // [slot][sym-in-slot][array f/e/p/m][lane] -- 4*4*4*64*16 B = 64 KiB
    __shared__ v4 lds_buf[NSLOT][SLOT][4][64];

    const int    wave = threadIdx.x >> 6;
    const int    lane = threadIdx.x & 63;
    const size_t c4   = (size_t)blockIdx.x * 64 + lane;  // float4 col idx

    const v4* F = (const v4*)frac;
    const v4* E = (const v4*)exs;
    const v4* P = (const v4*)pos;
    const v4* M = (const v4*)mrate;
    v4*       O = (v4*)out;

    if (wave == 1) {
        // ------------------------- producer -------------------------
        // issue one slot = SLOT symbols x 4 arrays = 16 requests (16 KB)
#define ISSUE_SLOT(SL)                                                    \
        {                                                                 \
            const int _ring = (SL) & (NSLOT - 1);                         \
            _Pragma("unroll")                                             \
            for (int _j = 0; _j < SLOT; ++_j) {                           \
                const size_t _ro = (size_t)((SL) * SLOT + _j) * B4 + c4;  \
                gload16(F + _ro, &lds_buf[_ring][_j][0][0]);              \
                gload16(E + _ro, &lds_buf[_ring][_j][1][0]);              \
                gload16(P + _ro, &lds_buf[_ring][_j][2][0]);              \
                gload16(M + _ro, &lds_buf[_ring][_j][3][0]);              \
            }                                                             \
        }

        // prologue: slots 0..2 in flight, slot 0 complete before BAR(0)
        ISSUE_SLOT(0);
        ISSUE_SLOT(1);
        ISSUE_SLOT(2);
        asm volatile("s_waitcnt vmcnt(32)" ::: "memory");
        __builtin_amdgcn_s_barrier();                       // BAR(0)

        // phase p (p=0..28): issue slot p+3, guarantee slot p+1 complete.
        // After the wait, slots p+2 and p+3 (32 req) remain outstanding:
        // loads always span the barrier, vmcnt never drains to 0.
        for (int p = 0; p < PHASES - 3; ++p) {
            ISSUE_SLOT(p + 3);
            asm volatile("s_waitcnt vmcnt(32)" ::: "memory");
            __builtin_amdgcn_s_barrier();                   // BAR(p+1)
        }
        // epilogue drain: 16 -> 0
        asm volatile("s_waitcnt vmcnt(16)" ::: "memory");
        __builtin_amdgcn_s_barrier();                       // BAR(30)
        asm volatile("s_waitcnt vmcnt(0)" ::: "memory");
        __builtin_amdgcn_s_barrier();                       // BAR(31)
        // phase 31: consumer finishes slot 31; producer idles.
#undef ISSUE_SLOT
    } else {
        // ------------------------- consumer -------------------------
        const v4 umv = *((const v4*)um0 + c4);
        float um[4] = {umv.x, umv.y, umv.z, umv.w};

        __builtin_amdgcn_s_barrier();                       // BAR(0)
        asm volatile("" ::: "memory");

        for (int p = 0; p < PHASES; ++p) {
            const int ring = p & (NSLOT - 1);
#pragma unroll
            for (int j = 0; j < SLOT; ++j) {
                const int s = p * SLOT + j;
                const v4 f  = lds_buf[ring][j][0][lane];
                const v4 e  = lds_buf[ring][j][1][lane];
                const v4 pv = lds_buf[ring][j][2][lane];
                const v4 m  = lds_buf[ring][j][3][lane];

                const float st = msm_step[s];   // uniform -> s_load
                const float mn = msm_min[s];
                const float mx = msm_max[s];

                v4 r;
                r.x = step1(f.x, e.x, pv.x, m.x, st, mn, mx, &um[0]);
                r.y = step1(f.y, e.y, pv.y, m.y, st, mn, mx, &um[1]);
                r.z = step1(f.z, e.z, pv.z, m.z, st, mn, mx, &um[2]);
                r.w = step1(f.w, e.w, pv.w, m.w, st, mn, mx, &um[3]);

                __builtin_nontemporal_store(r, O + (size_t)s * B4 + c4);
            }
            if (p < PHASES - 1) {
                // our ds_reads of this slot must retire before the
                // producer overwrites it next phase
                asm volatile("s_waitcnt lgkmcnt(0)" ::: "memory");
                __builtin_amdgcn_s_barrier();               // BAR(p+1)
                asm volatile("" ::: "memory");
            }
        }

        v4 umo;
        umo.x = um[0]; umo.y = um[1]; umo.z = um[2]; umo.w = um[3];
        __builtin_nontemporal_store(umo, O + (size_t)N_SYM * B4 + c4);
    }
}

extern "C" void kernel_launch(void* const* d_in, const int* in_sizes, int n_in,
                              void* d_out, int out_size, void* d_ws, size_t ws_size,
                              hipStream_t stream) {
    const float* frac     = (const float*)d_in[0];
    const float* exs      = (const float*)d_in[1];
    const float* pos      = (const float*)d_in[2];
    const float* mrate    = (const float*)d_in[3];
    const float* um0      = (const float*)d_in[4];
    const float* msm_min  = (const float*)d_in[5];
    const float* msm_step = (const float*)d_in[6];
    const float* msm_max  = (const float*)d_in[7];
    float* out = (float*)d_out;

    const int block = 128;                 // 2 waves: consumer + producer
    const int grid  = (BATCH / 4) / 64;    // 512 blocks -> 2 blocks/CU

    hipLaunchKernelGGL(lle_pc_kernel, dim3(grid), dim3(block), 0, stream,
                       frac, exs, pos, mrate, um0, msm_min, msm_step, msm_max,
                       out);
}

// Round 3
// 269.013 us; speedup vs baseline: 1.0145x; 1.0145x over previous
//
#include <hip/hip_runtime.h>
#include <math.h>

#define N_SYM 128
#define BATCH 131072
#define LEV   30.0f
#define CPB   512             // columns per block
#define SPP   4               // symbols per phase
#define NPH   (N_SYM / SPP)   // 32 phases
// LDS: RING(4) x SPP(4) x 4 arrays x CPB(512) floats = 32768 f = 128 KiB
// slot = 4 symbols x 8 KB; issue 2 slots ahead; steady-state vmcnt(16).

// R5: cooperative staging. R0-R4 establish a per-wave load-BW ceiling of
// ~5 GB/s (dwordx4) independent of ring depth / nominal in-flight:
// 512 issuing waves x 5.2 = 2.66 TB/s = the R3 plateau. Fix = decouple
// load width from compute width: 1 column/thread compute (um scalar in
// VGPR), but staging via global_load_lds dwordx4 -- 512 thr/block,
// 8 waves/CU ALL issuing 1 KB requests (2048 issuing waves, 4x R3).
// Wave w streams array (w>>1), col-half (w&1) -> LDS lands linear
// [sym][array][col]; consumer ds_read_b32 stride-1 (2-way alias = free).
// Counted vmcnt (never 0 mid-loop) + raw s_barrier per phase.
__device__ __forceinline__ void gload16(const float* g, float* l)
{
    __builtin_amdgcn_global_load_lds(
        (const __attribute__((address_space(1))) void*)g,
        (__attribute__((address_space(3))) void*)l,
        16, 0, 0);
}

__device__ __forceinline__ float step1(float f, float e, float p, float m,
                                       float st, float mn, float mx,
                                       float* um)
{
    const float mrl = m * LEV;
    const float us  = *um * mrl;                // unused_size
    const float mps = fabsf(p) + us;            // max_pos_size
    const float adj = fminf((p * f > 0.0f) ? us : mps, 0.0f);
    const float nps = f * (mps - adj);

    float       a  = fabsf(nps);
    const float sg = copysignf(1.0f, nps);
    a = floorf(a / st) * st;
    a = (a < mn) ? 0.0f : a;
    a = fminf(a, mx);

    *um = (mps - a) / mrl;
    return e * (sg * a) + (1.0f - e) * p;
}

#define VMWAIT(N) asm volatile("s_waitcnt vmcnt(" #N ")" ::: "memory")
#define BARRIER() do { __builtin_amdgcn_s_barrier(); \
                       asm volatile("" ::: "memory"); } while (0)

__global__ __launch_bounds__(512) void lle_coop_kernel(
    const float* __restrict__ frac,
    const float* __restrict__ exs,
    const float* __restrict__ pos,
    const float* __restrict__ mrate,
    const float* __restrict__ um0,
    const float* __restrict__ msm_min,
    const float* __restrict__ msm_step,
    const float* __restrict__ msm_max,
    float* __restrict__ out)
{
    __shared__ float lds[4 * SPP * 4 * CPB];   // 128 KiB

    const int t     = threadIdx.x;
    const int wave  = t >> 6;
    const int lane  = t & 63;
    const int gcol0 = blockIdx.x * CPB;

    // ---- producer role of this wave: array aidx, column half (wave&1)
    const int aidx = wave >> 1;
    const float* src = (aidx == 0) ? frac : (aidx == 1) ? exs
                     : (aidx == 2) ? pos  : mrate;
    const size_t scol = (size_t)gcol0 + (size_t)((wave & 1) * 256 + lane * 4);
    const int    wlds = aidx * 512 + (wave & 1) * 256;  // wave-uniform LDS base

    auto issue = [&](int slot) {
        const int rb = (slot & 3) * 8192 + wlds;
#pragma unroll
        for (int j = 0; j < SPP; ++j)
            gload16(src + (size_t)(slot * SPP + j) * BATCH + scol,
                    &lds[rb + j * 2048]);
    };

    // ---- consumer role: this thread owns global column gcol0 + t
    float um = um0[gcol0 + t];

    auto compute = [&](int k) {
        const int rb = (k & 3) * 8192;
#pragma unroll
        for (int j = 0; j < SPP; ++j) {
            const int   s  = k * SPP + j;
            const float st = msm_step[s];   // uniform -> s_load
            const float mn = msm_min[s];
            const float mx = msm_max[s];
            const float f  = lds[rb + j * 2048 +        t];
            const float e  = lds[rb + j * 2048 +  512 + t];
            const float pv = lds[rb + j * 2048 + 1024 + t];
            const float m  = lds[rb + j * 2048 + 1536 + t];
            const float r  = step1(f, e, pv, m, st, mn, mx, &um);
            __builtin_nontemporal_store(r, &out[(size_t)s * BATCH + gcol0 + t]);
        }
    };

    // prologue: two slots in flight
    issue(0);
    issue(1);

    // phase 0: after issuing slot 2, newer-than-slot0 = 4(slot1)+4(slot2)=8
    issue(2);  VMWAIT(8);  BARRIER();  compute(0);
    // phase 1: newer-than-slot1 = 4(slot2)+4(stores p0)+4(slot3) = 12
    issue(3);  VMWAIT(12); BARRIER();  compute(1);

    // steady state k=2..29: newer-than-slot-k =
    //   4(stores k-2) + 4(loads k+1) + 4(stores k-1) + 4(loads k+2) = 16
    for (int k = 2; k <= NPH - 3; ++k) {
        issue(k + 2);
        VMWAIT(16);
        BARRIER();
        compute(k);
    }

    // phase 30: newer-than-slot30 = 4(stores 28)+4(loads 31)+4(stores 29)=12
    VMWAIT(12); BARRIER(); compute(30);
    // phase 31: newer-than-slot31 = 4(stores 29)+4(stores 30) = 8
    VMWAIT(8);  BARRIER(); compute(31);

    // final unused_margin row
    __builtin_nontemporal_store(um, &out[(size_t)N_SYM * BATCH + gcol0 + t]);
}

extern "C" void kernel_launch(void* const* d_in, const int* in_sizes, int n_in,
                              void* d_out, int out_size, void* d_ws, size_t ws_size,
                              hipStream_t stream) {
    const float* frac     = (const float*)d_in[0];
    const float* exs      = (const float*)d_in[1];
    const float* pos      = (const float*)d_in[2];
    const float* mrate    = (const float*)d_in[3];
    const float* um0      = (const float*)d_in[4];
    const float* msm_min  = (const float*)d_in[5];
    const float* msm_step = (const float*)d_in[6];
    const float* msm_max  = (const float*)d_in[7];
    float* out = (float*)d_out;

    const int block = 512;                 // 8 waves, all produce + consume
    const int grid  = BATCH / CPB;         // 256 blocks -> 1 per CU

    hipLaunchKernelGGL(lle_coop_kernel, dim3(grid), dim3(block), 0, stream,
                       frac, exs, pos, mrate, um0, msm_min, msm_step, msm_max,
                       out);
}